// Round 4
// baseline (460.034 us; speedup 1.0000x reference)
//
#include <hip/hip_runtime.h>
#include <hip/hip_fp16.h>

#define DIM 64
#define BN_EPS 1e-5f

// ---------------- degree: deg[dst[e]] += 1 (int4 edge reads) ----------------
__global__ void k_degree(const int* __restrict__ dst, int* __restrict__ deg, int E) {
    int e = blockIdx.x * blockDim.x + threadIdx.x;
    int E4 = E >> 2;
    if (e < E4) {
        int4 v = ((const int4*)dst)[e];
        atomicAdd(&deg[v.x], 1);
        atomicAdd(&deg[v.y], 1);
        atomicAdd(&deg[v.z], 1);
        atomicAdd(&deg[v.w], 1);
    }
    if (e < (E & 3)) atomicAdd(&deg[dst[(E4 << 2) + e]], 1);
}

// ---------------- scan stage 1: per-block scan + block sums + dinv + zero stats ----------------
__global__ void k_scan1(const int* __restrict__ deg, int* __restrict__ rowptr,
                        int* __restrict__ bsum, float* __restrict__ dinv,
                        float* __restrict__ gstats, int N) {
    if (blockIdx.x == 0 && threadIdx.x < 128) gstats[threadIdx.x] = 0.f;
    __shared__ int s[256];
    int i = blockIdx.x * 256 + threadIdx.x;
    int v = (i < N) ? deg[i] : 0;
    if (i < N) dinv[i] = rsqrtf((float)v + 1.0f);  // +1 self-loop
    s[threadIdx.x] = v;
    __syncthreads();
    for (int off = 1; off < 256; off <<= 1) {
        int t = (threadIdx.x >= off) ? s[threadIdx.x - off] : 0;
        __syncthreads();
        s[threadIdx.x] += t;
        __syncthreads();
    }
    if (i < N) rowptr[i] = s[threadIdx.x] - v;  // exclusive
    if (threadIdx.x == 255) bsum[blockIdx.x] = s[255];
}

// ---------------- scan stage 2: scan block sums (single block, nb <= 512) ----------------
__global__ void k_scan2(const int* __restrict__ bsum, int* __restrict__ bofs,
                        int nb, int* __restrict__ rowptr, int N) {
    __shared__ int s[512];
    int v = ((int)threadIdx.x < nb) ? bsum[threadIdx.x] : 0;
    s[threadIdx.x] = v;
    __syncthreads();
    for (int off = 1; off < 512; off <<= 1) {
        int t = (threadIdx.x >= (unsigned)off) ? s[threadIdx.x - off] : 0;
        __syncthreads();
        s[threadIdx.x] += t;
        __syncthreads();
    }
    if ((int)threadIdx.x < nb) bofs[threadIdx.x] = s[threadIdx.x] - v;
    if ((int)threadIdx.x == nb - 1) rowptr[N] = s[threadIdx.x];  // total = E
}

// ---------------- scan stage 3: add block offsets; init bucket cursor ----------------
__global__ void k_scan3(int* __restrict__ rowptr, const int* __restrict__ bofs,
                        int* __restrict__ cursor, int N) {
    int i = blockIdx.x * 256 + threadIdx.x;
    if (i < N) {
        int r = rowptr[i] + bofs[blockIdx.x];
        rowptr[i] = r;
        cursor[i] = r;
    }
}

// ---------------- bucket: counting-sort edge sources by dst ----------------
__global__ void k_bucket(const int* __restrict__ src, const int* __restrict__ dst,
                         int* __restrict__ cursor, int* __restrict__ ssrc, int E) {
    int e = blockIdx.x * blockDim.x + threadIdx.x;
    int E4 = E >> 2;
    if (e < E4) {
        int4 d4 = ((const int4*)dst)[e];
        int4 s4 = ((const int4*)src)[e];
        ssrc[atomicAdd(&cursor[d4.x], 1)] = s4.x;
        ssrc[atomicAdd(&cursor[d4.y], 1)] = s4.y;
        ssrc[atomicAdd(&cursor[d4.z], 1)] = s4.z;
        ssrc[atomicAdd(&cursor[d4.w], 1)] = s4.w;
    }
    if (e < (E & 3)) {
        int idx = (E4 << 2) + e;
        ssrc[atomicAdd(&cursor[dst[idx]], 1)] = src[idx];
    }
}

// ---------------- h2 = fp16( (x @ W) * dinv[row] ) : row per thread ----------------
__global__ __launch_bounds__(256) void k_gemm(const float* __restrict__ x,
                                              const float* __restrict__ W,
                                              const float* __restrict__ dinv,
                                              __half* __restrict__ h2, int N) {
    __shared__ float Wl[DIM * DIM];
    for (int i = threadIdx.x; i < DIM * DIM; i += 256) Wl[i] = W[i];
    __syncthreads();
    int r = blockIdx.x * 256 + threadIdx.x;
    if (r >= N) return;
    const float4* xr4 = (const float4*)(x + (size_t)r * DIM);
    float4 acc[16];
#pragma unroll
    for (int j = 0; j < 16; ++j) acc[j] = make_float4(0.f, 0.f, 0.f, 0.f);
    for (int k0 = 0; k0 < 16; ++k0) {
        float4 xv = xr4[k0];
#pragma unroll
        for (int kk = 0; kk < 4; ++kk) {
            float xs = (&xv.x)[kk];
            const float4* wrow = (const float4*)(Wl + (k0 * 4 + kk) * DIM);
#pragma unroll
            for (int j = 0; j < 16; ++j) {
                float4 w = wrow[j];
                acc[j].x += xs * w.x;
                acc[j].y += xs * w.y;
                acc[j].z += xs * w.z;
                acc[j].w += xs * w.w;
            }
        }
    }
    float dr = dinv[r];
    float4* hr4 = (float4*)(h2 + (size_t)r * DIM);
    union { __half2 h[4]; float4 f4; } pack;
#pragma unroll
    for (int j = 0; j < 16; j += 2) {
        pack.h[0] = __float22half2_rn(make_float2(acc[j].x * dr, acc[j].y * dr));
        pack.h[1] = __float22half2_rn(make_float2(acc[j].z * dr, acc[j].w * dr));
        pack.h[2] = __float22half2_rn(make_float2(acc[j + 1].x * dr, acc[j + 1].y * dr));
        pack.h[3] = __float22half2_rn(make_float2(acc[j + 1].z * dr, acc[j + 1].w * dr));
        hr4[j >> 1] = pack.f4;
    }
}

// ---------------- pull-aggregate + bias + relu + BN partial sums ----------------
// wave per node; half-wave split: lanes 0-31 even edges, 32-63 odd edges,
// each lane holds 2 features (half2). One gather instr = 2 rows = 256B.
__global__ __launch_bounds__(256) void k_aggregate(
        const int* __restrict__ rowptr, const int* __restrict__ ssrc,
        const float* __restrict__ dinv, const __half2* __restrict__ h2,
        const float* __restrict__ b, float* __restrict__ out,
        float* __restrict__ gsum, float* __restrict__ gsumsq, int N) {
    __shared__ float2 s1[256], s2[256];
    const int lane = threadIdx.x & 63;
    const int wave = threadIdx.x >> 6;
    const int half = lane >> 5;
    const int l2i  = lane & 31;
    const float2 bf = ((const float2*)b)[l2i];
    float2 lsum = make_float2(0.f, 0.f), lsq = make_float2(0.f, 0.f);
    for (int d = blockIdx.x * 4 + wave; d < N; d += gridDim.x * 4) {
        int beg = rowptr[d], end = rowptr[d + 1];
        float2 c0 = make_float2(0.f, 0.f), c1 = c0, c2 = c0, c3 = c0;
        int i = beg;
        for (; i + 8 <= end; i += 8) {
            int e0 = ssrc[i + 0 + half];
            int e1 = ssrc[i + 2 + half];
            int e2 = ssrc[i + 4 + half];
            int e3 = ssrc[i + 6 + half];
            float2 v0 = __half22float2(h2[(size_t)e0 * 32 + l2i]);
            float2 v1 = __half22float2(h2[(size_t)e1 * 32 + l2i]);
            float2 v2 = __half22float2(h2[(size_t)e2 * 32 + l2i]);
            float2 v3 = __half22float2(h2[(size_t)e3 * 32 + l2i]);
            c0.x += v0.x; c0.y += v0.y;
            c1.x += v1.x; c1.y += v1.y;
            c2.x += v2.x; c2.y += v2.y;
            c3.x += v3.x; c3.y += v3.y;
        }
        for (; i < end; i += 2) {
            if (i + half < end) {
                int e = ssrc[i + half];
                float2 v = __half22float2(h2[(size_t)e * 32 + l2i]);
                c0.x += v.x; c0.y += v.y;
            }
        }
        float cx = (c0.x + c1.x) + (c2.x + c3.x);
        float cy = (c0.y + c1.y) + (c2.y + c3.y);
        cx += __shfl_xor(cx, 32);
        cy += __shfl_xor(cy, 32);
        float dd = dinv[d];
        float2 selfv = __half22float2(h2[(size_t)d * 32 + l2i]);  // h[d]*dd
        float ax = (cx + selfv.x) * dd + bf.x;
        float ay = (cy + selfv.y) * dd + bf.y;
        ax = fmaxf(ax, 0.f);
        ay = fmaxf(ay, 0.f);
        if (half == 0) {
            ((float2*)out)[(size_t)d * 32 + l2i] = make_float2(ax, ay);
            lsum.x += ax; lsum.y += ay;
            lsq.x += ax * ax; lsq.y += ay * ay;
        }
    }
    s1[threadIdx.x] = lsum;
    s2[threadIdx.x] = lsq;
    __syncthreads();
    if (threadIdx.x < 32) {
        float2 a0 = s1[threadIdx.x], a1 = s1[threadIdx.x + 64],
               a2 = s1[threadIdx.x + 128], a3 = s1[threadIdx.x + 192];
        float2 q0 = s2[threadIdx.x], q1 = s2[threadIdx.x + 64],
               q2 = s2[threadIdx.x + 128], q3 = s2[threadIdx.x + 192];
        float tx = (a0.x + a1.x) + (a2.x + a3.x);
        float ty = (a0.y + a1.y) + (a2.y + a3.y);
        float ux = (q0.x + q1.x) + (q2.x + q3.x);
        float uy = (q0.y + q1.y) + (q2.y + q3.y);
        atomicAdd(&gsum[2 * threadIdx.x], tx);
        atomicAdd(&gsum[2 * threadIdx.x + 1], ty);
        atomicAdd(&gsumsq[2 * threadIdx.x], ux);
        atomicAdd(&gsumsq[2 * threadIdx.x + 1], uy);
    }
}

// ---------------- bn2 (stats fused): out = a*scale + shift, float4, in-place ----------------
__global__ void k_bn2(float4* __restrict__ a, const float* __restrict__ gsum,
                      const float* __restrict__ gsumsq, const float* __restrict__ gamma,
                      const float* __restrict__ beta, int N, int total4) {
    __shared__ float sc[DIM], sh[DIM];
    if (threadIdx.x < DIM) {
        float inv_n = 1.0f / (float)N;
        float mean = gsum[threadIdx.x] * inv_n;
        float var = gsumsq[threadIdx.x] * inv_n - mean * mean;
        float istd = rsqrtf(var + BN_EPS);
        float s = gamma[threadIdx.x] * istd;
        sc[threadIdx.x] = s;
        sh[threadIdx.x] = beta[threadIdx.x] - mean * s;
    }
    __syncthreads();
    int i = blockIdx.x * blockDim.x + threadIdx.x;
    int stride = gridDim.x * blockDim.x;  // 2048*256 = 524288 ≡ 0 (mod 16)
    int f4 = i & 15;
    float4 scv = ((const float4*)sc)[f4];
    float4 shv = ((const float4*)sh)[f4];
    for (; i < total4; i += stride) {
        float4 v = a[i];
        v.x = v.x * scv.x + shv.x;
        v.y = v.y * scv.y + shv.y;
        v.z = v.z * scv.z + shv.z;
        v.w = v.w * scv.w + shv.w;
        a[i] = v;
    }
}

extern "C" void kernel_launch(void* const* d_in, const int* in_sizes, int n_in,
                              void* d_out, int out_size, void* d_ws, size_t ws_size,
                              hipStream_t stream) {
    const float* x     = (const float*)d_in[0];
    const int*   ei    = (const int*)d_in[1];
    const float* W     = (const float*)d_in[2];
    const float* b     = (const float*)d_in[3];
    const float* gamma = (const float*)d_in[4];
    const float* beta  = (const float*)d_in[5];
    float* out = (float*)d_out;

    const int N = in_sizes[0] / DIM;  // 100000
    const int E = in_sizes[1] / 2;    // 1000000
    const int* esrc = ei;
    const int* edst = ei + E;
    const int NB = (N + 255) / 256;   // 391

    // workspace layout
    char* ws = (char*)d_ws;
    size_t off = 0;
    int* deg = (int*)(ws + off);      off += (size_t)N * sizeof(int);
    off = (off + 255) & ~(size_t)255;
    float* dinv = (float*)(ws + off); off += (size_t)N * sizeof(float);
    off = (off + 255) & ~(size_t)255;
    int* rowptr = (int*)(ws + off);   off += (size_t)(N + 1) * sizeof(int);
    off = (off + 255) & ~(size_t)255;
    int* cursor = (int*)(ws + off);   off += (size_t)N * sizeof(int);
    off = (off + 255) & ~(size_t)255;
    int* bsum = (int*)(ws + off);     off += (size_t)NB * sizeof(int);
    off = (off + 255) & ~(size_t)255;
    int* bofs = (int*)(ws + off);     off += (size_t)NB * sizeof(int);
    off = (off + 255) & ~(size_t)255;
    int* ssrc = (int*)(ws + off);     off += (size_t)E * sizeof(int);
    off = (off + 255) & ~(size_t)255;
    __half* h2 = (__half*)(ws + off); off += (size_t)N * DIM * sizeof(__half);
    off = (off + 255) & ~(size_t)255;
    float* gsum   = (float*)(ws + off);
    float* gsumsq = gsum + 64;

    hipMemsetAsync(deg, 0, (size_t)N * sizeof(int), stream);

    k_degree<<<((E >> 2) + 255) / 256, 256, 0, stream>>>(edst, deg, E);
    k_scan1<<<NB, 256, 0, stream>>>(deg, rowptr, bsum, dinv, gsum, N);
    k_scan2<<<1, 512, 0, stream>>>(bsum, bofs, NB, rowptr, N);
    k_scan3<<<NB, 256, 0, stream>>>(rowptr, bofs, cursor, N);
    k_bucket<<<((E >> 2) + 255) / 256, 256, 0, stream>>>(esrc, edst, cursor, ssrc, E);
    k_gemm<<<NB, 256, 0, stream>>>(x, W, dinv, h2, N);
    k_aggregate<<<4096, 256, 0, stream>>>(rowptr, ssrc, dinv, (const __half2*)h2, b, out, gsum, gsumsq, N);
    k_bn2<<<2048, 256, 0, stream>>>((float4*)out, gsum, gsumsq, gamma, beta, N, N * DIM / 4);
}

// Round 5
// 366.824 us; speedup vs baseline: 1.2541x; 1.2541x over previous
//
#include <hip/hip_runtime.h>
#include <hip/hip_fp16.h>

#define DIM 64
#define BN_EPS 1e-5f

// ---------------- degree: deg[dst[e]] += 1 (int4 edge reads) ----------------
__global__ void k_degree(const int* __restrict__ dst, int* __restrict__ deg, int E) {
    int e = blockIdx.x * blockDim.x + threadIdx.x;
    int E4 = E >> 2;
    if (e < E4) {
        int4 v = ((const int4*)dst)[e];
        atomicAdd(&deg[v.x], 1);
        atomicAdd(&deg[v.y], 1);
        atomicAdd(&deg[v.z], 1);
        atomicAdd(&deg[v.w], 1);
    }
    if (e < (E & 3)) atomicAdd(&deg[dst[(E4 << 2) + e]], 1);
}

// ---------------- scan stage 1: per-block scan + block sums + dinv + zero stats ----------------
__global__ void k_scan1(const int* __restrict__ deg, int* __restrict__ rowptr,
                        int* __restrict__ bsum, float* __restrict__ dinv,
                        float* __restrict__ gstats, int N) {
    if (blockIdx.x == 0 && threadIdx.x < 128) gstats[threadIdx.x] = 0.f;
    __shared__ int s[256];
    int i = blockIdx.x * 256 + threadIdx.x;
    int v = (i < N) ? deg[i] : 0;
    if (i < N) dinv[i] = rsqrtf((float)v + 1.0f);  // +1 self-loop
    s[threadIdx.x] = v;
    __syncthreads();
    for (int off = 1; off < 256; off <<= 1) {
        int t = (threadIdx.x >= off) ? s[threadIdx.x - off] : 0;
        __syncthreads();
        s[threadIdx.x] += t;
        __syncthreads();
    }
    if (i < N) rowptr[i] = s[threadIdx.x] - v;  // exclusive
    if (threadIdx.x == 255) bsum[blockIdx.x] = s[255];
}

// ---------------- scan stage 2: scan block sums (single block, nb <= 512) ----------------
__global__ void k_scan2(const int* __restrict__ bsum, int* __restrict__ bofs,
                        int nb, int* __restrict__ rowptr, int N) {
    __shared__ int s[512];
    int v = ((int)threadIdx.x < nb) ? bsum[threadIdx.x] : 0;
    s[threadIdx.x] = v;
    __syncthreads();
    for (int off = 1; off < 512; off <<= 1) {
        int t = (threadIdx.x >= (unsigned)off) ? s[threadIdx.x - off] : 0;
        __syncthreads();
        s[threadIdx.x] += t;
        __syncthreads();
    }
    if ((int)threadIdx.x < nb) bofs[threadIdx.x] = s[threadIdx.x] - v;
    if ((int)threadIdx.x == nb - 1) rowptr[N] = s[threadIdx.x];  // total = E
}

// ---------------- scan stage 3: add block offsets; init bucket cursor ----------------
__global__ void k_scan3(int* __restrict__ rowptr, const int* __restrict__ bofs,
                        int* __restrict__ cursor, int N) {
    int i = blockIdx.x * 256 + threadIdx.x;
    if (i < N) {
        int r = rowptr[i] + bofs[blockIdx.x];
        rowptr[i] = r;
        cursor[i] = r;
    }
}

// ---------------- bucket: counting-sort edge sources by dst ----------------
__global__ void k_bucket(const int* __restrict__ src, const int* __restrict__ dst,
                         int* __restrict__ cursor, int* __restrict__ ssrc, int E) {
    int e = blockIdx.x * blockDim.x + threadIdx.x;
    int E4 = E >> 2;
    if (e < E4) {
        int4 d4 = ((const int4*)dst)[e];
        int4 s4 = ((const int4*)src)[e];
        ssrc[atomicAdd(&cursor[d4.x], 1)] = s4.x;
        ssrc[atomicAdd(&cursor[d4.y], 1)] = s4.y;
        ssrc[atomicAdd(&cursor[d4.z], 1)] = s4.z;
        ssrc[atomicAdd(&cursor[d4.w], 1)] = s4.w;
    }
    if (e < (E & 3)) {
        int idx = (E4 << 2) + e;
        ssrc[atomicAdd(&cursor[dst[idx]], 1)] = src[idx];
    }
}

// ---------------- h2 = fp16( (x @ W) * dinv[row] ) : row per thread ----------------
__global__ __launch_bounds__(256) void k_gemm(const float* __restrict__ x,
                                              const float* __restrict__ W,
                                              const float* __restrict__ dinv,
                                              __half* __restrict__ h2, int N) {
    __shared__ float Wl[DIM * DIM];
    for (int i = threadIdx.x; i < DIM * DIM; i += 256) Wl[i] = W[i];
    __syncthreads();
    int r = blockIdx.x * 256 + threadIdx.x;
    if (r >= N) return;
    const float4* xr4 = (const float4*)(x + (size_t)r * DIM);
    float4 acc[16];
#pragma unroll
    for (int j = 0; j < 16; ++j) acc[j] = make_float4(0.f, 0.f, 0.f, 0.f);
    for (int k0 = 0; k0 < 16; ++k0) {
        float4 xv = xr4[k0];
#pragma unroll
        for (int kk = 0; kk < 4; ++kk) {
            float xs = (&xv.x)[kk];
            const float4* wrow = (const float4*)(Wl + (k0 * 4 + kk) * DIM);
#pragma unroll
            for (int j = 0; j < 16; ++j) {
                float4 w = wrow[j];
                acc[j].x += xs * w.x;
                acc[j].y += xs * w.y;
                acc[j].z += xs * w.z;
                acc[j].w += xs * w.w;
            }
        }
    }
    float dr = dinv[r];
    float4* hr4 = (float4*)(h2 + (size_t)r * DIM);
    union { __half2 h[4]; float4 f4; } pack;
#pragma unroll
    for (int j = 0; j < 16; j += 2) {
        pack.h[0] = __float22half2_rn(make_float2(acc[j].x * dr, acc[j].y * dr));
        pack.h[1] = __float22half2_rn(make_float2(acc[j].z * dr, acc[j].w * dr));
        pack.h[2] = __float22half2_rn(make_float2(acc[j + 1].x * dr, acc[j + 1].y * dr));
        pack.h[3] = __float22half2_rn(make_float2(acc[j + 1].z * dr, acc[j + 1].w * dr));
        hr4[j >> 1] = pack.f4;
    }
}

// ---------------- pull-aggregate + bias + relu + BN partial sums ----------------
// wave per node (grid-stride), lane = feature. Index loads are WAVE-UNIFORM
// (compiler scalarizes); gathers are uniform-base + lane*2B. 8 indep chains.
__global__ __launch_bounds__(256) void k_aggregate(
        const int* __restrict__ rowptr, const int* __restrict__ ssrc,
        const float* __restrict__ dinv, const __half* __restrict__ h2,
        const float* __restrict__ b, float* __restrict__ out,
        float* __restrict__ gsum, float* __restrict__ gsumsq, int N) {
    __shared__ float s1[256], s2[256];
    const int lane = threadIdx.x & 63;
    const int wave = threadIdx.x >> 6;
    const float bf = b[lane];
    float lsum = 0.f, lsq = 0.f;
    for (int d = blockIdx.x * 4 + wave; d < N; d += gridDim.x * 4) {
        int beg = rowptr[d], end = rowptr[d + 1];
        float a0 = 0.f, a1 = 0.f, a2 = 0.f, a3 = 0.f;
        float a4 = 0.f, a5 = 0.f, a6 = 0.f, a7 = 0.f;
        int i = beg;
        for (; i + 8 <= end; i += 8) {
            int s0 = ssrc[i], sA = ssrc[i + 1], sB = ssrc[i + 2], sC = ssrc[i + 3];
            int s4 = ssrc[i + 4], s5 = ssrc[i + 5], s6 = ssrc[i + 6], s7 = ssrc[i + 7];
            a0 += __half2float(h2[(size_t)s0 * DIM + lane]);
            a1 += __half2float(h2[(size_t)sA * DIM + lane]);
            a2 += __half2float(h2[(size_t)sB * DIM + lane]);
            a3 += __half2float(h2[(size_t)sC * DIM + lane]);
            a4 += __half2float(h2[(size_t)s4 * DIM + lane]);
            a5 += __half2float(h2[(size_t)s5 * DIM + lane]);
            a6 += __half2float(h2[(size_t)s6 * DIM + lane]);
            a7 += __half2float(h2[(size_t)s7 * DIM + lane]);
        }
        for (; i + 4 <= end; i += 4) {
            int s0 = ssrc[i], sA = ssrc[i + 1], sB = ssrc[i + 2], sC = ssrc[i + 3];
            a0 += __half2float(h2[(size_t)s0 * DIM + lane]);
            a1 += __half2float(h2[(size_t)sA * DIM + lane]);
            a2 += __half2float(h2[(size_t)sB * DIM + lane]);
            a3 += __half2float(h2[(size_t)sC * DIM + lane]);
        }
        for (; i < end; ++i) {
            a0 += __half2float(h2[(size_t)ssrc[i] * DIM + lane]);
        }
        size_t di = (size_t)d * DIM + lane;
        float dd = dinv[d];
        float self = __half2float(h2[di]);  // = h[d]*dd ; self term = self*dd
        float a = ((((a0 + a1) + (a2 + a3)) + ((a4 + a5) + (a6 + a7))) + self) * dd + bf;
        a = fmaxf(a, 0.f);
        out[di] = a;
        lsum += a;
        lsq += a * a;
    }
    s1[threadIdx.x] = lsum;
    s2[threadIdx.x] = lsq;
    __syncthreads();
    if (threadIdx.x < 64) {
        float t1 = s1[threadIdx.x] + s1[threadIdx.x + 64] + s1[threadIdx.x + 128] + s1[threadIdx.x + 192];
        float t2 = s2[threadIdx.x] + s2[threadIdx.x + 64] + s2[threadIdx.x + 128] + s2[threadIdx.x + 192];
        atomicAdd(&gsum[threadIdx.x], t1);
        atomicAdd(&gsumsq[threadIdx.x], t2);
    }
}

// ---------------- bn2 (stats fused): out = a*scale + shift, float4, in-place ----------------
__global__ void k_bn2(float4* __restrict__ a, const float* __restrict__ gsum,
                      const float* __restrict__ gsumsq, const float* __restrict__ gamma,
                      const float* __restrict__ beta, int N, int total4) {
    __shared__ float sc[DIM], sh[DIM];
    if (threadIdx.x < DIM) {
        float inv_n = 1.0f / (float)N;
        float mean = gsum[threadIdx.x] * inv_n;
        float var = gsumsq[threadIdx.x] * inv_n - mean * mean;
        float istd = rsqrtf(var + BN_EPS);
        float s = gamma[threadIdx.x] * istd;
        sc[threadIdx.x] = s;
        sh[threadIdx.x] = beta[threadIdx.x] - mean * s;
    }
    __syncthreads();
    int i = blockIdx.x * blockDim.x + threadIdx.x;
    int stride = gridDim.x * blockDim.x;  // 2048*256 = 524288 ≡ 0 (mod 16)
    int f4 = i & 15;
    float4 scv = ((const float4*)sc)[f4];
    float4 shv = ((const float4*)sh)[f4];
    for (; i < total4; i += stride) {
        float4 v = a[i];
        v.x = v.x * scv.x + shv.x;
        v.y = v.y * scv.y + shv.y;
        v.z = v.z * scv.z + shv.z;
        v.w = v.w * scv.w + shv.w;
        a[i] = v;
    }
}

extern "C" void kernel_launch(void* const* d_in, const int* in_sizes, int n_in,
                              void* d_out, int out_size, void* d_ws, size_t ws_size,
                              hipStream_t stream) {
    const float* x     = (const float*)d_in[0];
    const int*   ei    = (const int*)d_in[1];
    const float* W     = (const float*)d_in[2];
    const float* b     = (const float*)d_in[3];
    const float* gamma = (const float*)d_in[4];
    const float* beta  = (const float*)d_in[5];
    float* out = (float*)d_out;

    const int N = in_sizes[0] / DIM;  // 100000
    const int E = in_sizes[1] / 2;    // 1000000
    const int* esrc = ei;
    const int* edst = ei + E;
    const int NB = (N + 255) / 256;   // 391

    // workspace layout
    char* ws = (char*)d_ws;
    size_t off = 0;
    int* deg = (int*)(ws + off);      off += (size_t)N * sizeof(int);
    off = (off + 255) & ~(size_t)255;
    float* dinv = (float*)(ws + off); off += (size_t)N * sizeof(float);
    off = (off + 255) & ~(size_t)255;
    int* rowptr = (int*)(ws + off);   off += (size_t)(N + 1) * sizeof(int);
    off = (off + 255) & ~(size_t)255;
    int* cursor = (int*)(ws + off);   off += (size_t)N * sizeof(int);
    off = (off + 255) & ~(size_t)255;
    int* bsum = (int*)(ws + off);     off += (size_t)NB * sizeof(int);
    off = (off + 255) & ~(size_t)255;
    int* bofs = (int*)(ws + off);     off += (size_t)NB * sizeof(int);
    off = (off + 255) & ~(size_t)255;
    int* ssrc = (int*)(ws + off);     off += (size_t)E * sizeof(int);
    off = (off + 255) & ~(size_t)255;
    __half* h2 = (__half*)(ws + off); off += (size_t)N * DIM * sizeof(__half);
    off = (off + 255) & ~(size_t)255;
    float* gsum   = (float*)(ws + off);
    float* gsumsq = gsum + 64;

    hipMemsetAsync(deg, 0, (size_t)N * sizeof(int), stream);

    k_degree<<<((E >> 2) + 255) / 256, 256, 0, stream>>>(edst, deg, E);
    k_scan1<<<NB, 256, 0, stream>>>(deg, rowptr, bsum, dinv, gsum, N);
    k_scan2<<<1, 512, 0, stream>>>(bsum, bofs, NB, rowptr, N);
    k_scan3<<<NB, 256, 0, stream>>>(rowptr, bofs, cursor, N);
    k_bucket<<<((E >> 2) + 255) / 256, 256, 0, stream>>>(esrc, edst, cursor, ssrc, E);
    k_gemm<<<NB, 256, 0, stream>>>(x, W, dinv, h2, N);
    k_aggregate<<<4096, 256, 0, stream>>>(rowptr, ssrc, dinv, h2, b, out, gsum, gsumsq, N);
    k_bn2<<<2048, 256, 0, stream>>>((float4*)out, gsum, gsumsq, gamma, beta, N, N * DIM / 4);
}

// Round 6
// 319.580 us; speedup vs baseline: 1.4395x; 1.1478x over previous
//
#include <hip/hip_runtime.h>
#include <hip/hip_fp16.h>

#define DIM 64
#define BN_EPS 1e-5f

// ---------------- degree: deg[dst[e]] += 1 (int4 edge reads) ----------------
__global__ void k_degree(const int* __restrict__ dst, int* __restrict__ deg, int E) {
    int e = blockIdx.x * blockDim.x + threadIdx.x;
    int E4 = E >> 2;
    if (e < E4) {
        int4 v = ((const int4*)dst)[e];
        atomicAdd(&deg[v.x], 1);
        atomicAdd(&deg[v.y], 1);
        atomicAdd(&deg[v.z], 1);
        atomicAdd(&deg[v.w], 1);
    }
    if (e < (E & 3)) atomicAdd(&deg[dst[(E4 << 2) + e]], 1);
}

// ---------------- scan stage 1: per-block scan + block sums + dinv + zero stats ----------------
__global__ void k_scan1(const int* __restrict__ deg, int* __restrict__ rowptr,
                        int* __restrict__ bsum, float* __restrict__ dinv,
                        float* __restrict__ gstats, int N) {
    if (blockIdx.x == 0 && threadIdx.x < 128) gstats[threadIdx.x] = 0.f;
    __shared__ int s[256];
    int i = blockIdx.x * 256 + threadIdx.x;
    int v = (i < N) ? deg[i] : 0;
    if (i < N) dinv[i] = rsqrtf((float)v + 1.0f);  // +1 self-loop
    s[threadIdx.x] = v;
    __syncthreads();
    for (int off = 1; off < 256; off <<= 1) {
        int t = (threadIdx.x >= off) ? s[threadIdx.x - off] : 0;
        __syncthreads();
        s[threadIdx.x] += t;
        __syncthreads();
    }
    if (i < N) rowptr[i] = s[threadIdx.x] - v;  // exclusive
    if (threadIdx.x == 255) bsum[blockIdx.x] = s[255];
}

// ---------------- scan stages 2+3 merged: each block redundantly scans bsum,
// then adds offsets to its 512 rowptr entries and inits cursor ----------------
// requires nb <= 512 (N <= 131072)
__global__ void k_scan23(int* __restrict__ rowptr, const int* __restrict__ bsum,
                         int nb, int* __restrict__ cursor, int N, int E) {
    __shared__ int s[512];
    __shared__ int sx[512];
    int v = ((int)threadIdx.x < nb) ? bsum[threadIdx.x] : 0;
    s[threadIdx.x] = v;
    __syncthreads();
    for (int off = 1; off < 512; off <<= 1) {
        int t = (threadIdx.x >= (unsigned)off) ? s[threadIdx.x - off] : 0;
        __syncthreads();
        s[threadIdx.x] += t;
        __syncthreads();
    }
    sx[threadIdx.x] = s[threadIdx.x] - v;  // exclusive block offset
    __syncthreads();
    int i = blockIdx.x * 512 + threadIdx.x;
    if (i < N) {
        int r = rowptr[i] + sx[i >> 8];
        rowptr[i] = r;
        cursor[i] = r;
    }
    if (i == 0) rowptr[N] = E;
}

// ---------------- bucket: counting-sort (src,dst) pairs by dst ----------------
__global__ void k_bucket(const int* __restrict__ src, const int* __restrict__ dst,
                         int* __restrict__ cursor, int2* __restrict__ sd, int E) {
    int e = blockIdx.x * blockDim.x + threadIdx.x;
    int E4 = E >> 2;
    if (e < E4) {
        int4 d4 = ((const int4*)dst)[e];
        int4 s4 = ((const int4*)src)[e];
        sd[atomicAdd(&cursor[d4.x], 1)] = make_int2(s4.x, d4.x);
        sd[atomicAdd(&cursor[d4.y], 1)] = make_int2(s4.y, d4.y);
        sd[atomicAdd(&cursor[d4.z], 1)] = make_int2(s4.z, d4.z);
        sd[atomicAdd(&cursor[d4.w], 1)] = make_int2(s4.w, d4.w);
    }
    if (e < (E & 3)) {
        int idx = (E4 << 2) + e;
        sd[atomicAdd(&cursor[dst[idx]], 1)] = make_int2(src[idx], dst[idx]);
    }
}

// ---------------- h2 = fp16( (x @ W) * dinv[row] ) : row per thread ----------------
__global__ __launch_bounds__(256) void k_gemm(const float* __restrict__ x,
                                              const float* __restrict__ W,
                                              const float* __restrict__ dinv,
                                              __half* __restrict__ h2, int N) {
    __shared__ float Wl[DIM * DIM];
    for (int i = threadIdx.x; i < DIM * DIM; i += 256) Wl[i] = W[i];
    __syncthreads();
    int r = blockIdx.x * 256 + threadIdx.x;
    if (r >= N) return;
    const float4* xr4 = (const float4*)(x + (size_t)r * DIM);
    float4 acc[16];
#pragma unroll
    for (int j = 0; j < 16; ++j) acc[j] = make_float4(0.f, 0.f, 0.f, 0.f);
    for (int k0 = 0; k0 < 16; ++k0) {
        float4 xv = xr4[k0];
#pragma unroll
        for (int kk = 0; kk < 4; ++kk) {
            float xs = (&xv.x)[kk];
            const float4* wrow = (const float4*)(Wl + (k0 * 4 + kk) * DIM);
#pragma unroll
            for (int j = 0; j < 16; ++j) {
                float4 w = wrow[j];
                acc[j].x += xs * w.x;
                acc[j].y += xs * w.y;
                acc[j].z += xs * w.z;
                acc[j].w += xs * w.w;
            }
        }
    }
    float dr = dinv[r];
    float4* hr4 = (float4*)(h2 + (size_t)r * DIM);
    union { __half2 h[4]; float4 f4; } pack;
#pragma unroll
    for (int j = 0; j < 16; j += 2) {
        pack.h[0] = __float22half2_rn(make_float2(acc[j].x * dr, acc[j].y * dr));
        pack.h[1] = __float22half2_rn(make_float2(acc[j].z * dr, acc[j].w * dr));
        pack.h[2] = __float22half2_rn(make_float2(acc[j + 1].x * dr, acc[j + 1].y * dr));
        pack.h[3] = __float22half2_rn(make_float2(acc[j + 1].z * dr, acc[j + 1].w * dr));
        hr4[j >> 1] = pack.f4;
    }
}

// ---------------- edge-parallel aggregate over sorted edges ----------------
// wave = 64 consecutive sorted edges. ONE coalesced int2 load supplies all 64
// (src,dst) pairs; readlane broadcasts (scalar pipe, no memory round-trip).
// dst non-decreasing -> accumulate per lane (lane=feature), flush on segment
// change with a wave-uniform atomicAdd. agg must be pre-zeroed.
__global__ __launch_bounds__(256) void k_edgeagg(
        const int2* __restrict__ sd, const __half* __restrict__ h2,
        float* __restrict__ agg, int E) {
    const int lane = threadIdx.x & 63;
    const int wid = blockIdx.x * (blockDim.x >> 6) + (threadIdx.x >> 6);
    const int base = wid * 64;
    if (base >= E) return;
    const int nval = min(64, E - base);
    int2 p = sd[base + min(lane, nval - 1)];
    int sv = p.x, dv = p.y;
    const __half* hb = h2 + lane;  // lane-invariant feature offset
    float acc = 0.f;
    int dprev = __builtin_amdgcn_readlane(dv, 0);
    if (nval == 64) {
#pragma unroll
        for (int g = 0; g < 64; g += 8) {
            int sA[8], dA[8];
#pragma unroll
            for (int k = 0; k < 8; ++k) {
                sA[k] = __builtin_amdgcn_readlane(sv, g + k);
                dA[k] = __builtin_amdgcn_readlane(dv, g + k);
            }
            float vA[8];
#pragma unroll
            for (int k = 0; k < 8; ++k)
                vA[k] = __half2float(hb[(size_t)sA[k] * DIM]);  // 8 indep gathers
#pragma unroll
            for (int k = 0; k < 8; ++k) {
                if (dA[k] != dprev) {  // wave-uniform branch
                    atomicAdd(&agg[(size_t)dprev * DIM + lane], acc);
                    acc = 0.f;
                    dprev = dA[k];
                }
                acc += vA[k];
            }
        }
    } else {
        for (int j = 0; j < nval; ++j) {
            int sj = __builtin_amdgcn_readlane(sv, j);
            int dj = __builtin_amdgcn_readlane(dv, j);
            if (dj != dprev) {
                atomicAdd(&agg[(size_t)dprev * DIM + lane], acc);
                acc = 0.f;
                dprev = dj;
            }
            acc += __half2float(hb[(size_t)sj * DIM]);
        }
    }
    atomicAdd(&agg[(size_t)dprev * DIM + lane], acc);
}

// ---------------- post: a = relu((agg + h2_self)*dinv + b), stats ----------------
__global__ __launch_bounds__(256) void k_post(
        const __half* __restrict__ h2, const float* __restrict__ dinv,
        const float* __restrict__ b, float* __restrict__ out,
        float* __restrict__ gsum, float* __restrict__ gsumsq, int N) {
    __shared__ float s1[256], s2[256];
    const int lane = threadIdx.x & 63;
    const int wave = threadIdx.x >> 6;
    const float bf = b[lane];
    float lsum = 0.f, lsq = 0.f;
    for (int d = blockIdx.x * 4 + wave; d < N; d += gridDim.x * 4) {
        size_t di = (size_t)d * DIM + lane;
        float dd = dinv[d];
        float a = (out[di] + __half2float(h2[di])) * dd + bf;
        a = fmaxf(a, 0.f);
        out[di] = a;
        lsum += a;
        lsq += a * a;
    }
    s1[threadIdx.x] = lsum;
    s2[threadIdx.x] = lsq;
    __syncthreads();
    if (threadIdx.x < 64) {
        float t1 = s1[threadIdx.x] + s1[threadIdx.x + 64] + s1[threadIdx.x + 128] + s1[threadIdx.x + 192];
        float t2 = s2[threadIdx.x] + s2[threadIdx.x + 64] + s2[threadIdx.x + 128] + s2[threadIdx.x + 192];
        atomicAdd(&gsum[threadIdx.x], t1);
        atomicAdd(&gsumsq[threadIdx.x], t2);
    }
}

// ---------------- bn2 (stats fused): out = a*scale + shift, float4, in-place ----------------
__global__ void k_bn2(float4* __restrict__ a, const float* __restrict__ gsum,
                      const float* __restrict__ gsumsq, const float* __restrict__ gamma,
                      const float* __restrict__ beta, int N, int total4) {
    __shared__ float sc[DIM], sh[DIM];
    if (threadIdx.x < DIM) {
        float inv_n = 1.0f / (float)N;
        float mean = gsum[threadIdx.x] * inv_n;
        float var = gsumsq[threadIdx.x] * inv_n - mean * mean;
        float istd = rsqrtf(var + BN_EPS);
        float s = gamma[threadIdx.x] * istd;
        sc[threadIdx.x] = s;
        sh[threadIdx.x] = beta[threadIdx.x] - mean * s;
    }
    __syncthreads();
    int i = blockIdx.x * blockDim.x + threadIdx.x;
    int stride = gridDim.x * blockDim.x;  // 2048*256 = 524288 ≡ 0 (mod 16)
    int f4 = i & 15;
    float4 scv = ((const float4*)sc)[f4];
    float4 shv = ((const float4*)sh)[f4];
    for (; i < total4; i += stride) {
        float4 v = a[i];
        v.x = v.x * scv.x + shv.x;
        v.y = v.y * scv.y + shv.y;
        v.z = v.z * scv.z + shv.z;
        v.w = v.w * scv.w + shv.w;
        a[i] = v;
    }
}

extern "C" void kernel_launch(void* const* d_in, const int* in_sizes, int n_in,
                              void* d_out, int out_size, void* d_ws, size_t ws_size,
                              hipStream_t stream) {
    const float* x     = (const float*)d_in[0];
    const int*   ei    = (const int*)d_in[1];
    const float* W     = (const float*)d_in[2];
    const float* b     = (const float*)d_in[3];
    const float* gamma = (const float*)d_in[4];
    const float* beta  = (const float*)d_in[5];
    float* out = (float*)d_out;

    const int N = in_sizes[0] / DIM;  // 100000
    const int E = in_sizes[1] / 2;    // 1000000
    const int* esrc = ei;
    const int* edst = ei + E;
    const int NB = (N + 255) / 256;    // 391 scan1 blocks
    const int NB2 = (N + 511) / 512;   // scan23 blocks

    // workspace layout
    char* ws = (char*)d_ws;
    size_t off = 0;
    int* deg = (int*)(ws + off);      off += (size_t)N * sizeof(int);   // reused as cursor
    off = (off + 255) & ~(size_t)255;
    float* dinv = (float*)(ws + off); off += (size_t)N * sizeof(float);
    off = (off + 255) & ~(size_t)255;
    int* rowptr = (int*)(ws + off);   off += (size_t)(N + 1) * sizeof(int);
    off = (off + 255) & ~(size_t)255;
    int* bsum = (int*)(ws + off);     off += (size_t)NB * sizeof(int);
    off = (off + 255) & ~(size_t)255;
    int2* sd = (int2*)(ws + off);     off += (size_t)E * sizeof(int2);
    off = (off + 255) & ~(size_t)255;
    __half* h2 = (__half*)(ws + off); off += (size_t)N * DIM * sizeof(__half);
    off = (off + 255) & ~(size_t)255;
    float* gsum   = (float*)(ws + off);
    float* gsumsq = gsum + 64;

    hipMemsetAsync(deg, 0, (size_t)N * sizeof(int), stream);
    hipMemsetAsync(out, 0, (size_t)N * DIM * sizeof(float), stream);  // atomic target

    k_degree<<<((E >> 2) + 255) / 256, 256, 0, stream>>>(edst, deg, E);
    k_scan1<<<NB, 256, 0, stream>>>(deg, rowptr, bsum, dinv, gsum, N);
    k_scan23<<<NB2, 512, 0, stream>>>(rowptr, bsum, NB, deg /*cursor*/, N, E);
    k_bucket<<<((E >> 2) + 255) / 256, 256, 0, stream>>>(esrc, edst, deg /*cursor*/, sd, E);
    k_gemm<<<NB, 256, 0, stream>>>(x, W, dinv, h2, N);
    int chunks = (E + 63) / 64;
    k_edgeagg<<<(chunks + 3) / 4, 256, 0, stream>>>(sd, h2, out, E);
    k_post<<<1024, 256, 0, stream>>>(h2, dinv, b, out, gsum, gsumsq, N);
    k_bn2<<<2048, 256, 0, stream>>>((float4*)out, gsum, gsumsq, gamma, beta, N, N * DIM / 4);
}

// Round 7
// 303.278 us; speedup vs baseline: 1.5169x; 1.0538x over previous
//
#include <hip/hip_runtime.h>
#include <hip/hip_fp16.h>

#define DIM 64
#define BN_EPS 1e-5f

// ---------------- degree: deg[dst[e]] += 1 (int4 edge reads) ----------------
__global__ void k_degree(const int* __restrict__ dst, int* __restrict__ deg, int E) {
    int e = blockIdx.x * blockDim.x + threadIdx.x;
    int E4 = E >> 2;
    if (e < E4) {
        int4 v = ((const int4*)dst)[e];
        atomicAdd(&deg[v.x], 1);
        atomicAdd(&deg[v.y], 1);
        atomicAdd(&deg[v.z], 1);
        atomicAdd(&deg[v.w], 1);
    }
    if (e < (E & 3)) atomicAdd(&deg[dst[(E4 << 2) + e]], 1);
}

// ---------------- scan stage 1: per-block scan + block sums + dinv + zero stats ----------------
__global__ void k_scan1(const int* __restrict__ deg, int* __restrict__ rowptr,
                        int* __restrict__ bsum, float* __restrict__ dinv,
                        float* __restrict__ gstats, int N) {
    if (blockIdx.x == 0 && threadIdx.x < 128) gstats[threadIdx.x] = 0.f;
    __shared__ int s[256];
    int i = blockIdx.x * 256 + threadIdx.x;
    int v = (i < N) ? deg[i] : 0;
    if (i < N) dinv[i] = rsqrtf((float)v + 1.0f);  // +1 self-loop
    s[threadIdx.x] = v;
    __syncthreads();
    for (int off = 1; off < 256; off <<= 1) {
        int t = (threadIdx.x >= off) ? s[threadIdx.x - off] : 0;
        __syncthreads();
        s[threadIdx.x] += t;
        __syncthreads();
    }
    if (i < N) rowptr[i] = s[threadIdx.x] - v;  // exclusive
    if (threadIdx.x == 255) bsum[blockIdx.x] = s[255];
}

// ---------------- scan 2+3 merged: finalize rowptr, init cursor, emit chunkstart ----------------
// chunkstart[c] = node owning edge c*64 (rowptr[d] <= c*64 < rowptr[d+1])
// requires nb <= 512 (N <= 131072)
__global__ void k_scan23(int* __restrict__ rowptr, const int* __restrict__ bsum,
                         int nb, const int* __restrict__ deg, int* __restrict__ cursor,
                         int* __restrict__ chunkstart, int N, int E) {
    __shared__ int s[512];
    __shared__ int sx[512];
    int v = ((int)threadIdx.x < nb) ? bsum[threadIdx.x] : 0;
    s[threadIdx.x] = v;
    __syncthreads();
    for (int off = 1; off < 512; off <<= 1) {
        int t = (threadIdx.x >= (unsigned)off) ? s[threadIdx.x - off] : 0;
        __syncthreads();
        s[threadIdx.x] += t;
        __syncthreads();
    }
    sx[threadIdx.x] = s[threadIdx.x] - v;  // exclusive block offset
    __syncthreads();
    int i = blockIdx.x * 512 + threadIdx.x;
    if (i < N) {
        int r = rowptr[i] + sx[i >> 8];
        rowptr[i] = r;
        cursor[i] = r;
        int rn = r + deg[i];
        // chunks whose start (multiple of 64) lies in [r, rn)
        int c0 = (r + 63) >> 6;
        int c1 = (rn + 63) >> 6;
        for (int c = c0; c < c1; ++c) chunkstart[c] = i;
    }
    if (i == 0) rowptr[N] = E;
}

// ---------------- bucket: counting-sort edge SOURCES by dst (4B payload) ----------------
__global__ void k_bucket(const int* __restrict__ src, const int* __restrict__ dst,
                         int* __restrict__ cursor, int* __restrict__ ssrc, int E) {
    int e = blockIdx.x * blockDim.x + threadIdx.x;
    int E4 = E >> 2;
    if (e < E4) {
        int4 d4 = ((const int4*)dst)[e];
        int4 s4 = ((const int4*)src)[e];
        ssrc[atomicAdd(&cursor[d4.x], 1)] = s4.x;
        ssrc[atomicAdd(&cursor[d4.y], 1)] = s4.y;
        ssrc[atomicAdd(&cursor[d4.z], 1)] = s4.z;
        ssrc[atomicAdd(&cursor[d4.w], 1)] = s4.w;
    }
    if (e < (E & 3)) {
        int idx = (E4 << 2) + e;
        ssrc[atomicAdd(&cursor[dst[idx]], 1)] = src[idx];
    }
}

// ---------------- h2 = fp16(h*dinv) AND seed out with fp32 self term ----------------
__global__ __launch_bounds__(256) void k_gemm(const float* __restrict__ x,
                                              const float* __restrict__ W,
                                              const float* __restrict__ dinv,
                                              __half* __restrict__ h2,
                                              float* __restrict__ outseed, int N) {
    __shared__ float Wl[DIM * DIM];
    for (int i = threadIdx.x; i < DIM * DIM; i += 256) Wl[i] = W[i];
    __syncthreads();
    int r = blockIdx.x * 256 + threadIdx.x;
    if (r >= N) return;
    const float4* xr4 = (const float4*)(x + (size_t)r * DIM);
    float4 acc[16];
#pragma unroll
    for (int j = 0; j < 16; ++j) acc[j] = make_float4(0.f, 0.f, 0.f, 0.f);
    for (int k0 = 0; k0 < 16; ++k0) {
        float4 xv = xr4[k0];
#pragma unroll
        for (int kk = 0; kk < 4; ++kk) {
            float xs = (&xv.x)[kk];
            const float4* wrow = (const float4*)(Wl + (k0 * 4 + kk) * DIM);
#pragma unroll
            for (int j = 0; j < 16; ++j) {
                float4 w = wrow[j];
                acc[j].x += xs * w.x;
                acc[j].y += xs * w.y;
                acc[j].z += xs * w.z;
                acc[j].w += xs * w.w;
            }
        }
    }
    float dr = dinv[r];
    float4* hr4 = (float4*)(h2 + (size_t)r * DIM);
    float4* os4 = (float4*)(outseed + (size_t)r * DIM);
    union { __half2 h[4]; float4 f4; } pack;
#pragma unroll
    for (int j = 0; j < 16; j += 2) {
        float4 v0 = make_float4(acc[j].x * dr, acc[j].y * dr, acc[j].z * dr, acc[j].w * dr);
        float4 v1 = make_float4(acc[j + 1].x * dr, acc[j + 1].y * dr, acc[j + 1].z * dr, acc[j + 1].w * dr);
        os4[j] = v0;
        os4[j + 1] = v1;
        pack.h[0] = __float22half2_rn(make_float2(v0.x, v0.y));
        pack.h[1] = __float22half2_rn(make_float2(v0.z, v0.w));
        pack.h[2] = __float22half2_rn(make_float2(v1.x, v1.y));
        pack.h[3] = __float22half2_rn(make_float2(v1.z, v1.w));
        hr4[j >> 1] = pack.f4;
    }
}

// ---------------- edge-parallel aggregate over sorted edge sources ----------------
// wave = 64 consecutive sorted edges. One coalesced load of src indices; dst
// reconstructed from rowptr window via ballot+popcount (no memory round-trip).
// dst non-decreasing -> per-lane accumulator, flush on segment change.
__global__ __launch_bounds__(256) void k_edgeagg(
        const int* __restrict__ ssrc, const int* __restrict__ rowptr,
        const int* __restrict__ chunkstart, const __half* __restrict__ h2,
        float* __restrict__ agg, int N, int E) {
    const int lane = threadIdx.x & 63;
    const int wid = blockIdx.x * (blockDim.x >> 6) + (threadIdx.x >> 6);
    const int base = wid << 6;
    if (base >= E) return;
    const int nval = min(64, E - base);
    const int node0 = chunkstart[wid];
    int sv = ssrc[base + min(lane, nval - 1)];
    int nn = node0 + 1 + lane;
    if (nn > N) nn = N;
    int rp = rowptr[nn];  // lane l holds rowptr[node0+1+l]
    const __half* hb = h2 + lane;
    float acc = 0.f;
    // coverage: if rowptr[node0+64] <= last edge idx, dsts exceed our window
    bool uncovered = (__builtin_amdgcn_readlane(rp, 63) <= base + nval - 1);
    if (!uncovered && nval == 64) {
        int dprev = node0 + __popcll(__ballot(rp <= base));
#pragma unroll
        for (int g = 0; g < 64; g += 8) {
            int sA[8];
            float vA[8];
            int dA[8];
#pragma unroll
            for (int k = 0; k < 8; ++k) sA[k] = __builtin_amdgcn_readlane(sv, g + k);
#pragma unroll
            for (int k = 0; k < 8; ++k) vA[k] = __half2float(hb[(size_t)sA[k] * DIM]);
#pragma unroll
            for (int k = 0; k < 8; ++k) dA[k] = node0 + __popcll(__ballot(rp <= base + g + k));
#pragma unroll
            for (int k = 0; k < 8; ++k) {
                if (dA[k] != dprev) {  // wave-uniform
                    atomicAdd(&agg[(size_t)dprev * DIM + lane], acc);
                    acc = 0.f;
                    dprev = dA[k];
                }
                acc += vA[k];
            }
        }
        atomicAdd(&agg[(size_t)dprev * DIM + lane], acc);
    } else if (!uncovered) {
        int dprev = node0 + __popcll(__ballot(rp <= base));
        for (int j = 0; j < nval; ++j) {
            int sj = __builtin_amdgcn_readlane(sv, j);
            int dj = node0 + __popcll(__ballot(rp <= base + j));
            if (dj != dprev) {
                atomicAdd(&agg[(size_t)dprev * DIM + lane], acc);
                acc = 0.f;
                dprev = dj;
            }
            acc += __half2float(hb[(size_t)sj * DIM]);
        }
        atomicAdd(&agg[(size_t)dprev * DIM + lane], acc);
    } else {
        // slow path: per-edge binary search (chunk spans >64 nodes; ~never)
        int dprev = -1;
        for (int j = 0; j < nval; ++j) {
            int e = base + j;
            int lo = 0, hi = N - 1;
            while (lo < hi) {
                int mid = (lo + hi + 1) >> 1;
                if (rowptr[mid] <= e) lo = mid; else hi = mid - 1;
            }
            if (lo != dprev) {
                if (dprev >= 0) atomicAdd(&agg[(size_t)dprev * DIM + lane], acc);
                acc = 0.f;
                dprev = lo;
            }
            acc += __half2float(hb[(size_t)__builtin_amdgcn_readlane(sv, j) * DIM]);
        }
        if (dprev >= 0) atomicAdd(&agg[(size_t)dprev * DIM + lane], acc);
    }
}

// ---------------- post: a = relu(out*dinv + b), stats (out pre-seeded w/ self) ----------------
__global__ __launch_bounds__(256) void k_post(
        const float* __restrict__ dinv, const float* __restrict__ b,
        float* __restrict__ out, float* __restrict__ gsum,
        float* __restrict__ gsumsq, int N) {
    __shared__ float s1[256], s2[256];
    const int lane = threadIdx.x & 63;
    const int wave = threadIdx.x >> 6;
    const float bf = b[lane];
    float lsum = 0.f, lsq = 0.f;
    for (int d = blockIdx.x * 4 + wave; d < N; d += gridDim.x * 4) {
        size_t di = (size_t)d * DIM + lane;
        float a = out[di] * dinv[d] + bf;
        a = fmaxf(a, 0.f);
        out[di] = a;
        lsum += a;
        lsq += a * a;
    }
    s1[threadIdx.x] = lsum;
    s2[threadIdx.x] = lsq;
    __syncthreads();
    if (threadIdx.x < 64) {
        float t1 = s1[threadIdx.x] + s1[threadIdx.x + 64] + s1[threadIdx.x + 128] + s1[threadIdx.x + 192];
        float t2 = s2[threadIdx.x] + s2[threadIdx.x + 64] + s2[threadIdx.x + 128] + s2[threadIdx.x + 192];
        atomicAdd(&gsum[threadIdx.x], t1);
        atomicAdd(&gsumsq[threadIdx.x], t2);
    }
}

// ---------------- bn2 (stats fused): out = a*scale + shift, float4, in-place ----------------
__global__ void k_bn2(float4* __restrict__ a, const float* __restrict__ gsum,
                      const float* __restrict__ gsumsq, const float* __restrict__ gamma,
                      const float* __restrict__ beta, int N, int total4) {
    __shared__ float sc[DIM], sh[DIM];
    if (threadIdx.x < DIM) {
        float inv_n = 1.0f / (float)N;
        float mean = gsum[threadIdx.x] * inv_n;
        float var = gsumsq[threadIdx.x] * inv_n - mean * mean;
        float istd = rsqrtf(var + BN_EPS);
        float s = gamma[threadIdx.x] * istd;
        sc[threadIdx.x] = s;
        sh[threadIdx.x] = beta[threadIdx.x] - mean * s;
    }
    __syncthreads();
    int i = blockIdx.x * blockDim.x + threadIdx.x;
    int stride = gridDim.x * blockDim.x;  // 2048*256 = 524288 ≡ 0 (mod 16)
    int f4 = i & 15;
    float4 scv = ((const float4*)sc)[f4];
    float4 shv = ((const float4*)sh)[f4];
    for (; i < total4; i += stride) {
        float4 v = a[i];
        v.x = v.x * scv.x + shv.x;
        v.y = v.y * scv.y + shv.y;
        v.z = v.z * scv.z + shv.z;
        v.w = v.w * scv.w + shv.w;
        a[i] = v;
    }
}

extern "C" void kernel_launch(void* const* d_in, const int* in_sizes, int n_in,
                              void* d_out, int out_size, void* d_ws, size_t ws_size,
                              hipStream_t stream) {
    const float* x     = (const float*)d_in[0];
    const int*   ei    = (const int*)d_in[1];
    const float* W     = (const float*)d_in[2];
    const float* b     = (const float*)d_in[3];
    const float* gamma = (const float*)d_in[4];
    const float* beta  = (const float*)d_in[5];
    float* out = (float*)d_out;

    const int N = in_sizes[0] / DIM;  // 100000
    const int E = in_sizes[1] / 2;    // 1000000
    const int* esrc = ei;
    const int* edst = ei + E;
    const int NB = (N + 255) / 256;    // 391 scan1 blocks
    const int NB2 = (N + 511) / 512;   // scan23 blocks
    const int nchunks = (E + 63) / 64; // 15625

    // workspace layout
    char* ws = (char*)d_ws;
    size_t off = 0;
    int* deg = (int*)(ws + off);        off += (size_t)N * sizeof(int);
    off = (off + 255) & ~(size_t)255;
    float* dinv = (float*)(ws + off);   off += (size_t)N * sizeof(float);
    off = (off + 255) & ~(size_t)255;
    int* rowptr = (int*)(ws + off);     off += (size_t)(N + 1) * sizeof(int);
    off = (off + 255) & ~(size_t)255;
    int* cursor = (int*)(ws + off);     off += (size_t)N * sizeof(int);
    off = (off + 255) & ~(size_t)255;
    int* bsum = (int*)(ws + off);       off += (size_t)NB * sizeof(int);
    off = (off + 255) & ~(size_t)255;
    int* chunkstart = (int*)(ws + off); off += (size_t)nchunks * sizeof(int);
    off = (off + 255) & ~(size_t)255;
    int* ssrc = (int*)(ws + off);       off += (size_t)E * sizeof(int);
    off = (off + 255) & ~(size_t)255;
    __half* h2 = (__half*)(ws + off);   off += (size_t)N * DIM * sizeof(__half);
    off = (off + 255) & ~(size_t)255;
    float* gsum   = (float*)(ws + off);
    float* gsumsq = gsum + 64;

    hipMemsetAsync(deg, 0, (size_t)N * sizeof(int), stream);

    k_degree<<<((E >> 2) + 255) / 256, 256, 0, stream>>>(edst, deg, E);
    k_scan1<<<NB, 256, 0, stream>>>(deg, rowptr, bsum, dinv, gsum, N);
    k_scan23<<<NB2, 512, 0, stream>>>(rowptr, bsum, NB, deg, cursor, chunkstart, N, E);
    k_bucket<<<((E >> 2) + 255) / 256, 256, 0, stream>>>(esrc, edst, cursor, ssrc, E);
    k_gemm<<<NB, 256, 0, stream>>>(x, W, dinv, h2, out, N);
    k_edgeagg<<<(nchunks + 3) / 4, 256, 0, stream>>>(ssrc, rowptr, chunkstart, h2, out, N, E);
    k_post<<<1024, 256, 0, stream>>>(dinv, b, out, gsum, gsumsq, N);
    k_bn2<<<2048, 256, 0, stream>>>((float4*)out, gsum, gsumsq, gamma, beta, N, N * DIM / 4);
}